// Round 3
// baseline (82.916 us; speedup 1.0000x reference)
//
#include <hip/hip_runtime.h>

#define FS 32
#define NS 30            // num_sample = filter_size - 2
#define FDIM 256
#define SLABW 16         // floats per d-slab (64 B = 1 cacheline)
#define NSLAB (FDIM / SLABW)   // 16 slabs
#define BPB 64           // output rows (b) per block
#define NXCD 8

__global__ __launch_bounds__(256) void stc_slab_kernel(
    const float* __restrict__ feat,     // [100000, 256]
    const int*   __restrict__ nidx,     // [B, 30]
    const float* __restrict__ weight,   // [32]
    const float* __restrict__ avgw,     // [32]
    const float* __restrict__ U,        // [32, 32] row-major
    float* __restrict__ out,            // [B, 256]
    int B, int chunks)
{
    __shared__ float t_sh[FS];
    __shared__ float c_sh[FS];
    __shared__ int   idx_sh[BPB * NS];
    __shared__ int   sidx_sh[BPB * NS];    // per-b sorted ascending
    __shared__ float scoef_sh[BPB * NS];   // coef permuted alongside

    const int tid = threadIdx.x;

    // Decode block -> (slab, b-chunk) with XCD affinity:
    // blocks dispatch round-robin over 8 XCDs, so keeping slab%8 == blockIdx%8
    // pins each d-slab's table working set (64 B/row) to ONE XCD's L2.
    const int per_phase = chunks * NXCD;
    const int p     = blockIdx.x / per_phase;   // 0..NSLAB/8-1
    const int r2    = blockIdx.x % per_phase;
    const int chunk = r2 / NXCD;
    const int xcd   = r2 % NXCD;
    const int slab  = p * NXCD + xcd;           // 0..15
    const int b0    = chunk * BPB;

    // t[g] = weight[g] * sum_f U[f][g]*avg[f]
    if (tid < FS) {
        float t = 0.f;
        #pragma unroll
        for (int f = 0; f < FS; ++f) t += U[f * FS + tid] * avgw[f];
        t_sh[tid] = t * weight[tid];
    }
    // stage this block's neighbor indices (coalesced)
    for (int i = tid; i < BPB * NS; i += 256) {
        int g = b0 * NS + i;
        idx_sh[i] = (g < B * NS) ? nidx[g] : 0;
    }
    __syncthreads();
    // c[f'] = sum_g U[f'][g] * t[g]
    if (tid < FS) {
        float c = 0.f;
        #pragma unroll
        for (int g = 0; g < FS; ++g) c += U[tid * FS + g] * t_sh[g];
        c_sh[tid] = c;
    }
    __syncthreads();

    // Per-b rank-sort of the 30 (idx, coef) pairs ascending by idx.
    // 4 threads per b, each ranks ~8 elements.
    {
        const int bl = tid >> 2, q = tid & 3;
        const int base = bl * NS;
        for (int j = q; j < NS; j += 4) {
            const int key = idx_sh[base + j];
            int rank = 0;
            #pragma unroll
            for (int m = 0; m < NS; ++m) {
                const int km = idx_sh[base + m];
                rank += (km < key) || (km == key && m < j);
            }
            sidx_sh[base + rank]  = key;
            scoef_sh[base + rank] = c_sh[j + 1];  // slots 0 and 31 zero-padded
        }
    }
    __syncthreads();

    // Gather-reduce: thread = (b_local, quad). 4 lanes cover this slab's
    // 16 floats; a wave = 16 b's -> 16 scattered 64B segments per load instr.
    const int bl = tid >> 2, q = tid & 3;
    const int b  = b0 + bl;
    const float* base = feat + slab * SLABW + q * 4;
    const int sbase = bl * NS;
    float4 acc = make_float4(0.f, 0.f, 0.f, 0.f);

    #pragma unroll 6
    for (int s = 0; s < NS; ++s) {
        const int   row = sidx_sh[sbase + s];
        const float cs  = scoef_sh[sbase + s];
        const float4 v  = *(const float4*)(base + (long long)row * FDIM);
        acc.x += cs * v.x;
        acc.y += cs * v.y;
        acc.z += cs * v.z;
        acc.w += cs * v.w;
    }

    if (b < B)
        *((float4*)(out + (long long)b * FDIM + slab * SLABW) + q) = acc;
}

extern "C" void kernel_launch(void* const* d_in, const int* in_sizes, int n_in,
                              void* d_out, int out_size, void* d_ws, size_t ws_size,
                              hipStream_t stream) {
    const float* feat   = (const float*)d_in[0];
    const int*   nidx   = (const int*)d_in[1];
    const float* weight = (const float*)d_in[2];
    const float* avgw   = (const float*)d_in[3];
    const float* U      = (const float*)d_in[4];
    float* out = (float*)d_out;

    const int B = in_sizes[1] / NS;                 // 10000
    const int chunks = (B + BPB - 1) / BPB;         // 157
    const int grid = (NSLAB / NXCD) * chunks * NXCD; // 2 phases * 157 * 8 = 2512

    stc_slab_kernel<<<grid, 256, 0, stream>>>(feat, nidx, weight, avgw, U, out, B, chunks);
}

// Round 4
// 48.213 us; speedup vs baseline: 1.7198x; 1.7198x over previous
//
#include <hip/hip_runtime.h>

#define FS 32
#define NS 30               // num_sample
#define FDIM 256
#define NSLAB 8             // one slab per XCD
#define SLABW 32            // floats per slab = 128 B
#define BPB 64              // output rows (b) per block
#define NXCD 8

__global__ __launch_bounds__(256, 5) void stc_slab128_kernel(
    const float* __restrict__ feat,     // [100000, 256]
    const int*   __restrict__ nidx,     // [B, 30]
    const float* __restrict__ weight,   // [32]
    const float* __restrict__ avgw,     // [32]
    const float* __restrict__ U,        // [32, 32]
    float* __restrict__ out,            // [B, 256]
    int B)
{
    __shared__ float t_sh[FS];
    __shared__ float c_sh[FS];
    __shared__ int   idx_sh[BPB * NS];
    __shared__ int   sidx_sh[BPB * NS];    // sorted ascending per b
    __shared__ float scoef_sh[BPB * NS];   // coef permuted alongside

    const int tid   = threadIdx.x;
    // slab == blockIdx%8 == XCD (round-robin dispatch): pins each d-slab's
    // table working set (128 B/row) to ONE XCD's L2.
    const int slab  = blockIdx.x & (NXCD - 1);
    const int chunk = blockIdx.x >> 3;
    const int b0    = chunk * BPB;

    // t[g] = weight[g] * sum_f U[f][g]*avg[f]
    if (tid < FS) {
        float t = 0.f;
        #pragma unroll
        for (int f = 0; f < FS; ++f) t += U[f * FS + tid] * avgw[f];
        t_sh[tid] = t * weight[tid];
    }
    // stage this chunk's neighbor indices (coalesced)
    for (int i = tid; i < BPB * NS; i += 256) {
        int g = b0 * NS + i;
        idx_sh[i] = (g < B * NS) ? nidx[g] : 0;
    }
    __syncthreads();
    // c[f'] = sum_g U[f'][g] * t[g]
    if (tid < FS) {
        float c = 0.f;
        #pragma unroll
        for (int g = 0; g < FS; ++g) c += U[tid * FS + g] * t_sh[g];
        c_sh[tid] = c;
    }
    __syncthreads();

    // Per-b rank-sort of 30 (idx, coef) pairs ascending by idx.
    for (int j = tid; j < BPB * NS; j += 256) {
        const int bl = j / NS, s = j - bl * NS;
        const int base = bl * NS;
        const int key = idx_sh[base + s];
        int rank = 0;
        #pragma unroll
        for (int m = 0; m < NS; ++m) {
            const int km = idx_sh[base + m];
            rank += (km < key) || (km == key && m < s);
        }
        sidx_sh[base + rank]  = key;
        scoef_sh[base + rank] = c_sh[s + 1];   // slots 0 and 31 zero-padded
    }
    __syncthreads();

    // Gather-reduce. thread = (bl 0..31, q 0..7); 8 threads * float4 = one
    // 128 B slab piece. Each thread handles TWO b's (bl, bl+32) -> two
    // independent load chains for MLP.
    const int bl = tid >> 3;
    const int q  = tid & 7;
    const float* fbase = feat + slab * SLABW + q * 4;
    const int s0 = bl * NS;
    const int s1 = (bl + 32) * NS;

    float4 a0 = make_float4(0.f, 0.f, 0.f, 0.f);
    float4 a1 = make_float4(0.f, 0.f, 0.f, 0.f);

    #pragma unroll 6
    for (int s = 0; s < NS; ++s) {
        const int   r0 = sidx_sh[s0 + s];
        const float c0 = scoef_sh[s0 + s];
        const int   r1 = sidx_sh[s1 + s];
        const float c1 = scoef_sh[s1 + s];
        const float4 v0 = *(const float4*)(fbase + (long long)r0 * FDIM);
        const float4 v1 = *(const float4*)(fbase + (long long)r1 * FDIM);
        a0.x += c0 * v0.x;  a0.y += c0 * v0.y;
        a0.z += c0 * v0.z;  a0.w += c0 * v0.w;
        a1.x += c1 * v1.x;  a1.y += c1 * v1.y;
        a1.z += c1 * v1.z;  a1.w += c1 * v1.w;
    }

    const int bA = b0 + bl, bB = b0 + bl + 32;
    if (bA < B) *((float4*)(out + (long long)bA * FDIM + slab * SLABW) + q) = a0;
    if (bB < B) *((float4*)(out + (long long)bB * FDIM + slab * SLABW) + q) = a1;
}

extern "C" void kernel_launch(void* const* d_in, const int* in_sizes, int n_in,
                              void* d_out, int out_size, void* d_ws, size_t ws_size,
                              hipStream_t stream) {
    const float* feat   = (const float*)d_in[0];
    const int*   nidx   = (const int*)d_in[1];
    const float* weight = (const float*)d_in[2];
    const float* avgw   = (const float*)d_in[3];
    const float* U      = (const float*)d_in[4];
    float* out = (float*)d_out;

    const int B = in_sizes[1] / NS;                // 10000
    const int chunks = (B + BPB - 1) / BPB;        // 157
    const int grid = chunks * NXCD;                // 1256 -> all resident, one batch

    stc_slab128_kernel<<<grid, 256, 0, stream>>>(feat, nidx, weight, avgw, U, out, B);
}